// Round 2
// baseline (666.907 us; speedup 1.0000x reference)
//
#include <hip/hip_runtime.h>
#include <stdint.h>

#define BB 32
#define CC_ 256
#define HH 56
#define WW 56
#define EPSV 1e-5f

typedef unsigned long long u64;

// ---------------- Weight prep: alpha, packed signs, BN folding ----------------
__global__ __launch_bounds__(256) void prep_weights(
    const float* __restrict__ w1, const float* __restrict__ w2,
    const float* __restrict__ bn1_g, const float* __restrict__ bn1_b,
    const float* __restrict__ bn1_m, const float* __restrict__ bn1_v,
    const float* __restrict__ bn2_g, const float* __restrict__ bn2_b,
    const float* __restrict__ bn2_m, const float* __restrict__ bn2_v,
    u64* __restrict__ pw1, u64* __restrict__ pw2,
    float* __restrict__ scale1, float* __restrict__ shift1,
    float* __restrict__ scale2, float* __restrict__ shift2)
{
    int co = blockIdx.x;
    int ci = threadIdx.x;
    int wv = ci >> 6, lane = ci & 63;

    float wvals[9];
    const float* wp = w1 + ((size_t)co*256 + ci)*9;
    float s1 = 0.f;
#pragma unroll
    for (int t = 0; t < 9; ++t) { wvals[t] = wp[t]; s1 += fabsf(wvals[t]); }
    float v2 = w2[(size_t)co*256 + ci];
    float s2 = fabsf(v2);

    // ballot-pack signs: bit l of word wv  <->  channel 64*wv + l  (+1 iff > 0)
#pragma unroll
    for (int t = 0; t < 9; ++t) {
        u64 b = __ballot(wvals[t] > 0.0f);
        if (lane == 0) pw1[((size_t)co*9 + t)*4 + wv] = b;
    }
    {
        u64 b = __ballot(v2 > 0.0f);
        if (lane == 0) pw2[(size_t)co*4 + wv] = b;
    }

    // reduce |w| sums across the wave
    for (int off = 32; off > 0; off >>= 1) {
        s1 += __shfl_down(s1, off);
        s2 += __shfl_down(s2, off);
    }
    __shared__ float r1[4], r2[4];
    if (lane == 0) { r1[wv] = s1; r2[wv] = s2; }
    __syncthreads();
    if (ci == 0) {
        float a1 = (r1[0]+r1[1]+r1[2]+r1[3]) * (1.0f/2304.0f);
        float a2 = (r2[0]+r2[1]+r2[2]+r2[3]) * (1.0f/256.0f);
        float inv1 = bn1_g[co] / sqrtf(bn1_v[co] + EPSV);
        float inv2 = bn2_g[co] / sqrtf(bn2_v[co] + EPSV);
        scale1[co] = a1 * inv1;
        shift1[co] = bn1_b[co] - bn1_m[co]*inv1;
        scale2[co] = a2 * inv2;
        shift2[co] = bn2_b[co] - bn2_m[co]*inv2;
    }
}

// ---------------- Pack input: rsign(x, beta1) -> bit-packed [n][h][w][4] ----------------
__global__ __launch_bounds__(256) void pack_input(
    const float* __restrict__ x, const float* __restrict__ beta1,
    u64* __restrict__ pack1)
{
    int bid = blockIdx.x;              // n*HH + h
    int n = bid / HH, h = bid % HH;
    int wv = threadIdx.x >> 6, lane = threadIdx.x & 63;
    int c = wv*64 + lane;              // lane l holds channel 64*wv + l
    const float4* row = (const float4*)(x + (((size_t)n*CC_ + c)*HH + h)*WW);
    float beta = beta1[c];
    u64 mine = 0;
#pragma unroll
    for (int g = 0; g < 14; ++g) {
        float4 v = row[g];
        u64 b0 = __ballot(v.x > beta);
        u64 b1 = __ballot(v.y > beta);
        u64 b2 = __ballot(v.z > beta);
        u64 b3 = __ballot(v.w > beta);
        int w0 = g*4;
        if (lane == w0)   mine = b0;
        if (lane == w0+1) mine = b1;
        if (lane == w0+2) mine = b2;
        if (lane == w0+3) mine = b3;
    }
    if (lane < WW) pack1[((size_t)bid*WW + lane)*4 + wv] = mine;
}

// ---------------- Fused main: conv3x3(bin) +BN +res +RPReLU -> rsign -> conv1x1(bin) +BN +res +RPReLU ----------------
__global__ __launch_bounds__(256, 2) void main_fused(
    const float* __restrict__ x,
    const u64* __restrict__ pack1,
    const u64* __restrict__ pw1, const u64* __restrict__ pw2,
    const float* __restrict__ scale1, const float* __restrict__ shift1,
    const float* __restrict__ scale2, const float* __restrict__ shift2,
    const float* __restrict__ beta2,
    const float* __restrict__ pr_gamma, const float* __restrict__ pr_slope,
    const float* __restrict__ pr_zeta,
    float* __restrict__ out)
{
    __shared__ u64 rows[3][WW][4];          // 5376 B
    __shared__ float outr[CC_][WW+1];       // 58368 B (pad 57 -> conflict-free on both axes)
    __shared__ u64 p2[WW][4];               // 1792 B   (total exactly 64 KiB)

    int bid = blockIdx.x;
    int n = bid / HH, h = bid % HH;
    int tid = threadIdx.x;
    int wv = __builtin_amdgcn_readfirstlane(tid >> 6);   // force scalar -> s_load weights
    int lane = tid & 63;

    // phase 0: stage packed rows h-1,h,h+1 (clamped)
    {
        int hm = (h > 0) ? h-1 : 0;
        int hp = (h < HH-1) ? h+1 : HH-1;
        for (int idx = tid; idx < 3*WW*4; idx += 256) {
            int r = idx / (WW*4);
            int rem = idx - r*(WW*4);
            int hr = (r == 0) ? hm : ((r == 1) ? h : hp);
            ((u64*)rows)[idx] = pack1[((size_t)(n*HH + hr)*WW)*4 + rem];
        }
    }
    __syncthreads();

    int w = (lane < WW) ? lane : WW-1;
    bool active = (lane < WW);
    int wm = (w > 0) ? w-1 : 0;
    int wp = (w < WW-1) ? w+1 : WW-1;
    bool rowU = (h > 0), rowD = (h < HH-1);
    bool colL = (w > 0), colR = (w < WW-1);
    bool tv[9];
    tv[0] = rowU && colL; tv[1] = rowU; tv[2] = rowU && colR;
    tv[3] = colL;         tv[4] = true; tv[5] = colR;
    tv[6] = rowD && colL; tv[7] = rowD; tv[8] = rowD && colR;

    // 3x3 window of packed pixels in registers (72 VGPRs)
    u64 win[9][4];
#pragma unroll
    for (int r = 0; r < 3; ++r) {
#pragma unroll
        for (int j = 0; j < 4; ++j) {
            win[r*3+0][j] = rows[r][wm][j];
            win[r*3+1][j] = rows[r][w][j];
            win[r*3+2][j] = rows[r][wp][j];
        }
    }

    // phase 1: layer 1 — wave handles couts wv*64 .. wv*64+63, lane = w
    const float* xbase = x + ((size_t)n*CC_*HH + h)*WW;   // + c*H*W + w
    for (int i = 0; i < 64; ++i) {
        int cc = wv*64 + i;                               // wave-uniform
        const u64* wq = pw1 + (size_t)cc*36;
        int acc = 0;
#pragma unroll
        for (int t = 0; t < 9; ++t) {
            int p = 0;
#pragma unroll
            for (int j = 0; j < 4; ++j)
                p += __builtin_popcountll(win[t][j] ^ wq[t*4+j]);
            acc += tv[t] ? p : 128;
        }
        // sum over valid taps of (+-1 products) = 256*nvalid - 2*sum(valid popxor)
        float s = (float)(2304 - 2*acc);
        float y = s*scale1[cc] + shift1[cc];
        y += xbase[(size_t)cc*HH*WW + w];                 // residual, coalesced
        float yr = y - pr_gamma[cc];
        float o = (yr > 0.f ? yr : pr_slope[cc]*yr) + pr_zeta[cc];
        if (active) outr[cc][w] = o;
    }
    __syncthreads();

    // phase 2: rsign(out_r, beta2) -> packed bits per pixel (lane = channel)
    {
        int c = wv*64 + lane;
        float beta = beta2[c];
        u64 mine = 0;
        for (int ww = 0; ww < WW; ++ww) {
            u64 b = __ballot(outr[c][ww] > beta);   // stride-57 read: conflict-free
            if (ww == lane) mine = b;
        }
        if (lane < WW) p2[lane][wv] = mine;
    }
    __syncthreads();

    // phase 3: layer 2 (1x1 conv) + BN + residual + RPReLU, lane = w
    u64 myp[4];
#pragma unroll
    for (int j = 0; j < 4; ++j) myp[j] = p2[w][j];
    float* obase = out + ((size_t)n*CC_*HH + h)*WW;
    for (int i = 0; i < 64; ++i) {
        int cc = wv*64 + i;                               // wave-uniform
        const u64* wq = pw2 + (size_t)cc*4;
        int p = 0;
#pragma unroll
        for (int j = 0; j < 4; ++j)
            p += __builtin_popcountll(myp[j] ^ wq[j]);
        float s = (float)(256 - 2*p);
        float y = s*scale2[cc] + shift2[cc];
        y += outr[cc][w];
        float yr = y - pr_gamma[cc];
        float o = (yr > 0.f ? yr : pr_slope[cc]*yr) + pr_zeta[cc];
        if (active) obase[(size_t)cc*HH*WW + w] = o;
    }
}

// ---------------- launcher ----------------
extern "C" void kernel_launch(void* const* d_in, const int* in_sizes, int n_in,
                              void* d_out, int out_size, void* d_ws, size_t ws_size,
                              hipStream_t stream) {
    const float* x           = (const float*)d_in[0];
    const float* rsign1_beta = (const float*)d_in[1];
    const float* w1          = (const float*)d_in[2];
    const float* bn1_g       = (const float*)d_in[3];
    const float* bn1_b       = (const float*)d_in[4];
    const float* bn1_m       = (const float*)d_in[5];
    const float* bn1_v       = (const float*)d_in[6];
    const float* rsign2_beta = (const float*)d_in[7];
    const float* w2          = (const float*)d_in[8];
    const float* bn2_g       = (const float*)d_in[9];
    const float* bn2_b       = (const float*)d_in[10];
    const float* bn2_m       = (const float*)d_in[11];
    const float* bn2_v       = (const float*)d_in[12];
    const float* pr_gamma    = (const float*)d_in[13];
    const float* pr_slope    = (const float*)d_in[14];
    const float* pr_zeta     = (const float*)d_in[15];

    char* ws = (char*)d_ws;
    u64*   pw1    = (u64*)(ws);            // 256*9*4*8   = 73728 B
    u64*   pw2    = (u64*)(ws + 73728);    // 256*4*8     =  8192 B
    float* scale1 = (float*)(ws + 81920);  // 1024 B each
    float* shift1 = (float*)(ws + 82944);
    float* scale2 = (float*)(ws + 83968);
    float* shift2 = (float*)(ws + 84992);
    u64*   pack1  = (u64*)(ws + 86016);    // 32*56*56*4*8 = 3211264 B

    prep_weights<<<256, 256, 0, stream>>>(w1, w2, bn1_g, bn1_b, bn1_m, bn1_v,
                                          bn2_g, bn2_b, bn2_m, bn2_v,
                                          pw1, pw2, scale1, shift1, scale2, shift2);
    pack_input<<<BB*HH, 256, 0, stream>>>(x, rsign1_beta, pack1);
    main_fused<<<BB*HH, 256, 0, stream>>>(x, pack1, pw1, pw2,
                                          scale1, shift1, scale2, shift2,
                                          rsign2_beta, pr_gamma, pr_slope, pr_zeta,
                                          (float*)d_out);
}

// Round 3
// 387.295 us; speedup vs baseline: 1.7220x; 1.7220x over previous
//
#include <hip/hip_runtime.h>
#include <stdint.h>

#define BB 32
#define CC_ 256
#define HH 56
#define WW 56
#define EPSV 1e-5f

typedef unsigned long long u64;

// ---------------- Weight prep: alpha, packed signs, BN folding ----------------
__global__ __launch_bounds__(256) void prep_weights(
    const float* __restrict__ w1, const float* __restrict__ w2,
    const float* __restrict__ bn1_g, const float* __restrict__ bn1_b,
    const float* __restrict__ bn1_m, const float* __restrict__ bn1_v,
    const float* __restrict__ bn2_g, const float* __restrict__ bn2_b,
    const float* __restrict__ bn2_m, const float* __restrict__ bn2_v,
    u64* __restrict__ pw1, u64* __restrict__ pw2,
    float* __restrict__ scale1, float* __restrict__ shift1,
    float* __restrict__ scale2, float* __restrict__ shift2)
{
    int co = blockIdx.x;
    int ci = threadIdx.x;
    int wv = ci >> 6, lane = ci & 63;

    float wvals[9];
    const float* wp = w1 + ((size_t)co*256 + ci)*9;
    float s1 = 0.f;
#pragma unroll
    for (int t = 0; t < 9; ++t) { wvals[t] = wp[t]; s1 += fabsf(wvals[t]); }
    float v2 = w2[(size_t)co*256 + ci];
    float s2 = fabsf(v2);

    // ballot-pack signs: bit l of word wv  <->  channel 64*wv + l  (+1 iff > 0)
#pragma unroll
    for (int t = 0; t < 9; ++t) {
        u64 b = __ballot(wvals[t] > 0.0f);
        if (lane == 0) pw1[((size_t)co*9 + t)*4 + wv] = b;
    }
    {
        u64 b = __ballot(v2 > 0.0f);
        if (lane == 0) pw2[(size_t)co*4 + wv] = b;
    }

    for (int off = 32; off > 0; off >>= 1) {
        s1 += __shfl_down(s1, off);
        s2 += __shfl_down(s2, off);
    }
    __shared__ float r1[4], r2[4];
    if (lane == 0) { r1[wv] = s1; r2[wv] = s2; }
    __syncthreads();
    if (ci == 0) {
        float a1 = (r1[0]+r1[1]+r1[2]+r1[3]) * (1.0f/2304.0f);
        float a2 = (r2[0]+r2[1]+r2[2]+r2[3]) * (1.0f/256.0f);
        float inv1 = bn1_g[co] / sqrtf(bn1_v[co] + EPSV);
        float inv2 = bn2_g[co] / sqrtf(bn2_v[co] + EPSV);
        scale1[co] = a1 * inv1;
        shift1[co] = bn1_b[co] - bn1_m[co]*inv1;
        scale2[co] = a2 * inv2;
        shift2[co] = bn2_b[co] - bn2_m[co]*inv2;
    }
}

// ---------------- Pack input: rsign(x, beta1) -> bit-packed [n][h][w][4] ----------------
__global__ __launch_bounds__(256) void pack_input(
    const float* __restrict__ x, const float* __restrict__ beta1,
    u64* __restrict__ pack1)
{
    int bid = blockIdx.x;              // n*HH + h
    int n = bid / HH, h = bid % HH;
    int wv = threadIdx.x >> 6, lane = threadIdx.x & 63;
    int c = wv*64 + lane;              // lane l holds channel 64*wv + l
    const float4* row = (const float4*)(x + (((size_t)n*CC_ + c)*HH + h)*WW);
    float beta = beta1[c];
    u64 mine = 0;
#pragma unroll
    for (int g = 0; g < 14; ++g) {
        float4 v = row[g];
        u64 b0 = __ballot(v.x > beta);
        u64 b1 = __ballot(v.y > beta);
        u64 b2 = __ballot(v.z > beta);
        u64 b3 = __ballot(v.w > beta);
        int w0 = g*4;
        if (lane == w0)   mine = b0;
        if (lane == w0+1) mine = b1;
        if (lane == w0+2) mine = b2;
        if (lane == w0+3) mine = b3;
    }
    if (lane < WW) pack1[((size_t)bid*WW + lane)*4 + wv] = mine;
}

// ---------------- Fused main (lane = cout): conv3x3 -> BN+res+RPReLU -> rsign -> conv1x1 -> BN+res+RPReLU ----------------
__global__ __launch_bounds__(256, 2) void main_fused(
    const float* __restrict__ x,
    const u64* __restrict__ pack1,
    const u64* __restrict__ pw1, const u64* __restrict__ pw2,
    const float* __restrict__ scale1, const float* __restrict__ shift1,
    const float* __restrict__ scale2, const float* __restrict__ shift2,
    const float* __restrict__ beta2,
    const float* __restrict__ pr_gamma, const float* __restrict__ pr_slope,
    const float* __restrict__ pr_zeta,
    float* __restrict__ out)
{
    __shared__ u64 rows[3][WW][4];          // 5376 B  packed input, 3 h-rows
    __shared__ float outr[CC_][WW+1];       // 58368 B x-row -> out_r -> final (in-place)
    __shared__ u64 p2[WW][4];               // 1792 B  repacked bits   (total = 65536)

    int bid = blockIdx.x;
    int n = bid / HH, h = bid % HH;
    int tid = threadIdx.x;
    int wv = tid >> 6;
    int lane = tid & 63;
    int cc = tid;                            // lane handles output channel cc = wv*64+lane

    // ---- per-channel constants & weights into registers (loaded ONCE, coalesced per-lane) ----
    u64 wr1[36];
    {
        const u64* wq1 = pw1 + (size_t)cc*36;
#pragma unroll
        for (int j = 0; j < 18; ++j) {
            ulonglong2 v = *(const ulonglong2*)(wq1 + 2*j);
            wr1[2*j] = v.x; wr1[2*j+1] = v.y;
        }
    }
    u64 wr2[4];
    {
        ulonglong2 a = *(const ulonglong2*)(pw2 + (size_t)cc*4);
        ulonglong2 b = *(const ulonglong2*)(pw2 + (size_t)cc*4 + 2);
        wr2[0]=a.x; wr2[1]=a.y; wr2[2]=b.x; wr2[3]=b.y;
    }
    float sc1 = scale1[cc], sh1 = shift1[cc];
    float sc2 = scale2[cc], sh2 = shift2[cc];
    float gam = pr_gamma[cc], slp = pr_slope[cc], zet = pr_zeta[cc];
    float bet2 = beta2[cc];

    // ---- phase 0a: stage packed rows h-1,h,h+1 (clamped; invalid taps masked later) ----
    {
        int hm = (h > 0) ? h-1 : 0;
        int hp = (h < HH-1) ? h+1 : HH-1;
        for (int idx = tid; idx < 3*WW*4; idx += 256) {
            int r = idx / (WW*4);
            int rem = idx - r*(WW*4);
            int hr = (r == 0) ? hm : ((r == 1) ? h : hp);
            ((u64*)rows)[idx] = pack1[((size_t)(n*HH + hr)*WW)*4 + rem];
        }
    }
    // ---- phase 0b: stage residual x row into outr (coalesced float4) ----
    for (int idx = tid; idx < CC_*14; idx += 256) {
        int c = idx / 14, g = idx - c*14;
        float4 v = *(const float4*)(x + (((size_t)n*CC_ + c)*HH + h)*WW + 4*g);
        outr[c][4*g+0] = v.x; outr[c][4*g+1] = v.y;
        outr[c][4*g+2] = v.z; outr[c][4*g+3] = v.w;
    }
    __syncthreads();

    // ---- phase 1: 3x3 binary conv + BN + residual + RPReLU; in-place outr update ----
    bool rowU = (h > 0), rowD = (h < HH-1);
    for (int w = 0; w < WW; ++w) {
        bool colL = (w > 0), colR = (w < WW-1);
        int wm = colL ? w-1 : w;
        int wp = colR ? w+1 : w;
        bool tv[9];
        tv[0] = rowU && colL; tv[1] = rowU; tv[2] = rowU && colR;
        tv[3] = colL;         tv[4] = true; tv[5] = colR;
        tv[6] = rowD && colL; tv[7] = rowD; tv[8] = rowD && colR;

        int acc = 0;
#pragma unroll
        for (int t = 0; t < 9; ++t) {
            int r = t / 3, ci = t - 3*r;
            int wc = (ci == 0) ? wm : ((ci == 1) ? w : wp);
            // wave-uniform address -> LDS broadcast read (conflict-free)
            ulonglong2 a = *(const ulonglong2*)&rows[r][wc][0];
            ulonglong2 b = *(const ulonglong2*)&rows[r][wc][2];
            int p = __builtin_popcountll(a.x ^ wr1[t*4+0])
                  + __builtin_popcountll(a.y ^ wr1[t*4+1])
                  + __builtin_popcountll(b.x ^ wr1[t*4+2])
                  + __builtin_popcountll(b.y ^ wr1[t*4+3]);
            acc += tv[t] ? p : 128;          // invalid tap contributes 0 to sum
        }
        float s = (float)(2304 - 2*acc);     // sum over valid taps of +-1 products
        float r0 = outr[cc][w];              // residual (stride-57: 2-way, free)
        float y = fmaf(s, sc1, sh1) + r0;
        float yr = y - gam;
        float o = (yr > 0.f ? yr : slp*yr) + zet;
        outr[cc][w] = o;                     // same-thread read->write: no hazard
    }
    // no barrier needed: phase 2 reads only this wave's own rows (same thread's writes)

    // ---- phase 2: rsign(out_r, beta2) -> packed bits per pixel ----
    {
        u64 mine = 0;
        for (int ww = 0; ww < WW; ++ww) {
            u64 b = __ballot(outr[cc][ww] > bet2);
            if (ww == lane) mine = b;
        }
        if (lane < WW) p2[lane][wv] = mine;
    }
    __syncthreads();                         // p2 is consumed cross-wave

    // ---- phase 3: 1x1 binary conv + BN + residual + RPReLU; in-place outr update ----
    for (int w = 0; w < WW; ++w) {
        ulonglong2 a = *(const ulonglong2*)&p2[w][0];   // broadcast
        ulonglong2 b = *(const ulonglong2*)&p2[w][2];
        int p = __builtin_popcountll(a.x ^ wr2[0]) + __builtin_popcountll(a.y ^ wr2[1])
              + __builtin_popcountll(b.x ^ wr2[2]) + __builtin_popcountll(b.y ^ wr2[3]);
        float s = (float)(256 - 2*p);
        float rr = outr[cc][w];              // out_r residual
        float y = fmaf(s, sc2, sh2) + rr;
        float yr = y - gam;
        float o = (yr > 0.f ? yr : slp*yr) + zet;
        outr[cc][w] = o;
    }
    __syncthreads();                         // phase 4 reads other waves' rows

    // ---- phase 4: coalesced float4 write-out ----
    for (int idx = tid; idx < CC_*14; idx += 256) {
        int c = idx / 14, g = idx - c*14;
        float4 v;
        v.x = outr[c][4*g+0]; v.y = outr[c][4*g+1];
        v.z = outr[c][4*g+2]; v.w = outr[c][4*g+3];
        *(float4*)(out + (((size_t)n*CC_ + c)*HH + h)*WW + 4*g) = v;
    }
}

// ---------------- launcher ----------------
extern "C" void kernel_launch(void* const* d_in, const int* in_sizes, int n_in,
                              void* d_out, int out_size, void* d_ws, size_t ws_size,
                              hipStream_t stream) {
    const float* x           = (const float*)d_in[0];
    const float* rsign1_beta = (const float*)d_in[1];
    const float* w1          = (const float*)d_in[2];
    const float* bn1_g       = (const float*)d_in[3];
    const float* bn1_b       = (const float*)d_in[4];
    const float* bn1_m       = (const float*)d_in[5];
    const float* bn1_v       = (const float*)d_in[6];
    const float* rsign2_beta = (const float*)d_in[7];
    const float* w2          = (const float*)d_in[8];
    const float* bn2_g       = (const float*)d_in[9];
    const float* bn2_b       = (const float*)d_in[10];
    const float* bn2_m       = (const float*)d_in[11];
    const float* bn2_v       = (const float*)d_in[12];
    const float* pr_gamma    = (const float*)d_in[13];
    const float* pr_slope    = (const float*)d_in[14];
    const float* pr_zeta     = (const float*)d_in[15];

    char* ws = (char*)d_ws;
    u64*   pw1    = (u64*)(ws);            // 256*9*4*8   = 73728 B
    u64*   pw2    = (u64*)(ws + 73728);    // 256*4*8     =  8192 B
    float* scale1 = (float*)(ws + 81920);  // 1024 B each
    float* shift1 = (float*)(ws + 82944);
    float* scale2 = (float*)(ws + 83968);
    float* shift2 = (float*)(ws + 84992);
    u64*   pack1  = (u64*)(ws + 86016);    // 32*56*56*4*8 = 3211264 B

    prep_weights<<<256, 256, 0, stream>>>(w1, w2, bn1_g, bn1_b, bn1_m, bn1_v,
                                          bn2_g, bn2_b, bn2_m, bn2_v,
                                          pw1, pw2, scale1, shift1, scale2, shift2);
    pack_input<<<BB*HH, 256, 0, stream>>>(x, rsign1_beta, pack1);
    main_fused<<<BB*HH, 256, 0, stream>>>(x, pack1, pw1, pw2,
                                          scale1, shift1, scale2, shift2,
                                          rsign2_beta, pr_gamma, pr_slope, pr_zeta,
                                          (float*)d_out);
}

// Round 6
// 381.531 us; speedup vs baseline: 1.7480x; 1.0151x over previous
//
#include <hip/hip_runtime.h>
#include <stdint.h>

#define BB 32
#define CC_ 256
#define HH 56
#define WW 56
#define TW 28          // W-tile width (2 tiles per row)
#define TCOLS 30       // TW + 2 halo columns
#define EPSV 1e-5f

typedef unsigned long long u64;

// ---------------- Weight prep: alpha, packed signs, BN folding ----------------
__global__ __launch_bounds__(256) void prep_weights(
    const float* __restrict__ w1, const float* __restrict__ w2,
    const float* __restrict__ bn1_g, const float* __restrict__ bn1_b,
    const float* __restrict__ bn1_m, const float* __restrict__ bn1_v,
    const float* __restrict__ bn2_g, const float* __restrict__ bn2_b,
    const float* __restrict__ bn2_m, const float* __restrict__ bn2_v,
    u64* __restrict__ pw1, u64* __restrict__ pw2,
    float* __restrict__ scale1, float* __restrict__ shift1,
    float* __restrict__ scale2, float* __restrict__ shift2)
{
    int co = blockIdx.x;
    int ci = threadIdx.x;
    int wv = ci >> 6, lane = ci & 63;

    float wvals[9];
    const float* wp = w1 + ((size_t)co*256 + ci)*9;
    float s1 = 0.f;
#pragma unroll
    for (int t = 0; t < 9; ++t) { wvals[t] = wp[t]; s1 += fabsf(wvals[t]); }
    float v2 = w2[(size_t)co*256 + ci];
    float s2 = fabsf(v2);

    // ballot-pack signs: bit l of word wv  <->  channel 64*wv + l  (+1 iff > 0)
#pragma unroll
    for (int t = 0; t < 9; ++t) {
        u64 b = __ballot(wvals[t] > 0.0f);
        if (lane == 0) pw1[((size_t)co*9 + t)*4 + wv] = b;
    }
    {
        u64 b = __ballot(v2 > 0.0f);
        if (lane == 0) pw2[(size_t)co*4 + wv] = b;
    }

    for (int off = 32; off > 0; off >>= 1) {
        s1 += __shfl_down(s1, off);
        s2 += __shfl_down(s2, off);
    }
    __shared__ float r1[4], r2[4];
    if (lane == 0) { r1[wv] = s1; r2[wv] = s2; }
    __syncthreads();
    if (ci == 0) {
        float a1 = (r1[0]+r1[1]+r1[2]+r1[3]) * (1.0f/2304.0f);
        float a2 = (r2[0]+r2[1]+r2[2]+r2[3]) * (1.0f/256.0f);
        float inv1 = bn1_g[co] / sqrtf(bn1_v[co] + EPSV);
        float inv2 = bn2_g[co] / sqrtf(bn2_v[co] + EPSV);
        scale1[co] = a1 * inv1;
        shift1[co] = bn1_b[co] - bn1_m[co]*inv1;
        scale2[co] = a2 * inv2;
        shift2[co] = bn2_b[co] - bn2_m[co]*inv2;
    }
}

// ---------------- Pack input: coalesced LDS stage -> ballot transpose ----------------
__global__ __launch_bounds__(256) void pack_input(
    const float* __restrict__ x, const float* __restrict__ beta1,
    u64* __restrict__ pack1)
{
    __shared__ float xrow[CC_][WW+1];      // 58368 B; stride 57 -> ballot reads conflict-free
    int bid = blockIdx.x;                  // n*HH + h
    int n = bid / HH, h = bid % HH;
    int tid = threadIdx.x;

    // coalesced stage: 14 consecutive lanes cover one channel's 224B row
    for (int idx = tid; idx < CC_*14; idx += 256) {
        int c = idx / 14, g = idx - c*14;
        float4 v = *(const float4*)(x + (((size_t)n*CC_ + c)*HH + h)*WW + 4*g);
        xrow[c][4*g+0] = v.x; xrow[c][4*g+1] = v.y;
        xrow[c][4*g+2] = v.z; xrow[c][4*g+3] = v.w;
    }
    __syncthreads();

    int wv = tid >> 6, lane = tid & 63;
    float beta = beta1[wv*64 + lane];
    u64 mine = 0;
    for (int ww = 0; ww < WW; ++ww) {
        u64 b = __ballot(xrow[wv*64 + lane][ww] > beta);
        if (ww == lane) mine = b;
    }
    if (lane < WW) pack1[((size_t)bid*WW + lane)*4 + wv] = mine;
}

// ---------------- helpers ----------------
__device__ __forceinline__ int tap_pop(const u64* __restrict__ col, const u64* __restrict__ wr) {
    ulonglong2 a = *(const ulonglong2*)(col);
    ulonglong2 b = *(const ulonglong2*)(col + 2);
    return __builtin_popcountll(a.x ^ wr[0]) + __builtin_popcountll(a.y ^ wr[1])
         + __builtin_popcountll(b.x ^ wr[2]) + __builtin_popcountll(b.y ^ wr[3]);
}

// ---------------- Fused main (lane = cout, W-tiled x2 for occupancy) ----------------
__global__ __launch_bounds__(256, 4) void main_fused(
    const float* __restrict__ x,
    const u64* __restrict__ pack1,
    const u64* __restrict__ pw1, const u64* __restrict__ pw2,
    const float* __restrict__ scale1, const float* __restrict__ shift1,
    const float* __restrict__ scale2, const float* __restrict__ shift2,
    const float* __restrict__ beta2,
    const float* __restrict__ pr_gamma, const float* __restrict__ pr_slope,
    const float* __restrict__ pr_zeta,
    float* __restrict__ out)
{
    __shared__ u64 rows[3][TCOLS][4];        // 2880 B  packed halo'd columns
    __shared__ float outr[CC_][TW+1];        // 29696 B x -> out_r -> final (in-place)
    __shared__ u64 p2[TW][4];                // 896 B   (total 33472 B -> 4 blocks/CU)

    int bid = blockIdx.x;
    int tile = bid & 1;                      // consecutive bids share (n,h): L2 locality
    int nh = bid >> 1;
    int n = nh / HH, h = nh % HH;
    int w0 = tile * TW;
    int tid = threadIdx.x;
    int wv = tid >> 6;
    int lane = tid & 63;
    int cc = tid;                            // this thread's output channel

    // ---- per-channel weights & constants into registers (once) ----
    u64 wr1[36];
    {
        const u64* wq1 = pw1 + (size_t)cc*36;
#pragma unroll
        for (int j = 0; j < 18; ++j) {
            ulonglong2 v = *(const ulonglong2*)(wq1 + 2*j);
            wr1[2*j] = v.x; wr1[2*j+1] = v.y;
        }
    }
    u64 wr2[4];
    {
        ulonglong2 a = *(const ulonglong2*)(pw2 + (size_t)cc*4);
        ulonglong2 b = *(const ulonglong2*)(pw2 + (size_t)cc*4 + 2);
        wr2[0]=a.x; wr2[1]=a.y; wr2[2]=b.x; wr2[3]=b.y;
    }
    float sc1 = scale1[cc], sh1 = shift1[cc];
    float sc2 = scale2[cc], sh2 = shift2[cc];
    float gam = pr_gamma[cc], slp = pr_slope[cc], zet = pr_zeta[cc];
    float bet2 = beta2[cc];

    // ---- stage packed rows h-1,h,h+1 with w-halo (clamped; edges masked in compute) ----
    {
        int hm = (h > 0) ? h-1 : 0;
        int hp = (h < HH-1) ? h+1 : HH-1;
        for (int idx = tid; idx < 3*TCOLS*4; idx += 256) {
            int r = idx / (TCOLS*4);
            int rem = idx - r*(TCOLS*4);
            int j = rem >> 2, q = rem & 3;
            int gw = w0 - 1 + j;
            gw = (gw < 0) ? 0 : ((gw > WW-1) ? WW-1 : gw);
            int hr = (r == 0) ? hm : ((r == 1) ? h : hp);
            rows[r][j][q] = pack1[((size_t)(n*HH + hr)*WW + gw)*4 + q];
        }
    }
    // ---- stage residual x tile (coalesced float4) ----
    for (int idx = tid; idx < CC_*7; idx += 256) {
        int c = idx / 7, g = idx - c*7;
        float4 v = *(const float4*)(x + (((size_t)n*CC_ + c)*HH + h)*WW + w0 + 4*g);
        outr[c][4*g+0] = v.x; outr[c][4*g+1] = v.y;
        outr[c][4*g+2] = v.z; outr[c][4*g+3] = v.w;
    }
    __syncthreads();

    bool rowU = (h > 0), rowD = (h < HH-1);

    // ---- phase 1: 3x3 binary conv + BN + residual + RPReLU (in-place outr) ----
    if (rowU && rowD) {
        // interior h: all row taps valid. One edge pixel per tile, rest straight-line.
        int pstart = 0, pend = TW;
        if (tile == 0) {
            // p=0 is global w=0: left column invalid -> 6 taps
            int acc = 0;
#pragma unroll
            for (int r = 0; r < 3; ++r) {
                acc += tap_pop(&rows[r][1][0], &wr1[(r*3+1)*4]);
                acc += tap_pop(&rows[r][2][0], &wr1[(r*3+2)*4]);
            }
            float s = (float)(1536 - 2*acc);
            float y = fmaf(s, sc1, sh1) + outr[cc][0];
            float yr = y - gam;
            outr[cc][0] = fmaf(slp, fminf(yr, 0.f), fmaxf(yr, 0.f)) + zet;
            pstart = 1;
        } else {
            // p=TW-1 is global w=55: right column invalid -> 6 taps
            int acc = 0;
#pragma unroll
            for (int r = 0; r < 3; ++r) {
                acc += tap_pop(&rows[r][TW-1][0], &wr1[(r*3+0)*4]);
                acc += tap_pop(&rows[r][TW][0],   &wr1[(r*3+1)*4]);
            }
            float s = (float)(1536 - 2*acc);
            float y = fmaf(s, sc1, sh1) + outr[cc][TW-1];
            float yr = y - gam;
            outr[cc][TW-1] = fmaf(slp, fminf(yr, 0.f), fmaxf(yr, 0.f)) + zet;
            pend = TW-1;
        }
        for (int p = pstart; p < pend; ++p) {
            int acc = 0;
#pragma unroll
            for (int r = 0; r < 3; ++r) {
#pragma unroll
                for (int dc = 0; dc < 3; ++dc)
                    acc += tap_pop(&rows[r][p+dc][0], &wr1[(r*3+dc)*4]);
            }
            float s = (float)(2304 - 2*acc);
            float y = fmaf(s, sc1, sh1) + outr[cc][p];
            float yr = y - gam;
            outr[cc][p] = fmaf(slp, fminf(yr, 0.f), fmaxf(yr, 0.f)) + zet;
        }
    } else {
        // border h (128/3584 blocks): per-tap wave-uniform scalar branches
        for (int p = 0; p < TW; ++p) {
            int w = w0 + p;
            bool colL = (w > 0), colR = (w < WW-1);
            int acc = 0, nval = 0;
#pragma unroll
            for (int t = 0; t < 9; ++t) {
                int r = t / 3, dc = t - 3*r;
                bool v = ((r == 0) ? rowU : (r == 2) ? rowD : true)
                      && ((dc == 0) ? colL : (dc == 2) ? colR : true);
                if (v) { acc += tap_pop(&rows[r][p+dc][0], &wr1[t*4]); ++nval; }
            }
            float s = (float)(256*nval - 2*acc);
            float y = fmaf(s, sc1, sh1) + outr[cc][p];
            float yr = y - gam;
            outr[cc][p] = fmaf(slp, fminf(yr, 0.f), fmaxf(yr, 0.f)) + zet;
        }
    }
    // no barrier: phase 2 reads only this thread's own outr row

    // ---- phase 2: rsign(out_r, beta2) -> packed bits per pixel ----
    {
        u64 mine = 0;
        for (int ww = 0; ww < TW; ++ww) {
            u64 b = __ballot(outr[cc][ww] > bet2);
            if (ww == lane) mine = b;
        }
        if (lane < TW) p2[lane][wv] = mine;
    }
    __syncthreads();                         // p2 consumed cross-wave

    // ---- phase 3: 1x1 binary conv + BN + residual + RPReLU (in-place outr) ----
    for (int p = 0; p < TW; ++p) {
        ulonglong2 a = *(const ulonglong2*)&p2[p][0];
        ulonglong2 b = *(const ulonglong2*)&p2[p][2];
        int pc = __builtin_popcountll(a.x ^ wr2[0]) + __builtin_popcountll(a.y ^ wr2[1])
               + __builtin_popcountll(b.x ^ wr2[2]) + __builtin_popcountll(b.y ^ wr2[3]);
        float s = (float)(256 - 2*pc);
        float y = fmaf(s, sc2, sh2) + outr[cc][p];
        float yr = y - gam;
        outr[cc][p] = fmaf(slp, fminf(yr, 0.f), fmaxf(yr, 0.f)) + zet;
    }
    __syncthreads();                         // phase 4 reads other waves' rows

    // ---- phase 4: coalesced float4 write-out ----
    for (int idx = tid; idx < CC_*7; idx += 256) {
        int c = idx / 7, g = idx - c*7;
        float4 v;
        v.x = outr[c][4*g+0]; v.y = outr[c][4*g+1];
        v.z = outr[c][4*g+2]; v.w = outr[c][4*g+3];
        *(float4*)(out + (((size_t)n*CC_ + c)*HH + h)*WW + w0 + 4*g) = v;
    }
}

// ---------------- launcher ----------------
extern "C" void kernel_launch(void* const* d_in, const int* in_sizes, int n_in,
                              void* d_out, int out_size, void* d_ws, size_t ws_size,
                              hipStream_t stream) {
    const float* x           = (const float*)d_in[0];
    const float* rsign1_beta = (const float*)d_in[1];
    const float* w1          = (const float*)d_in[2];
    const float* bn1_g       = (const float*)d_in[3];
    const float* bn1_b       = (const float*)d_in[4];
    const float* bn1_m       = (const float*)d_in[5];
    const float* bn1_v       = (const float*)d_in[6];
    const float* rsign2_beta = (const float*)d_in[7];
    const float* w2          = (const float*)d_in[8];
    const float* bn2_g       = (const float*)d_in[9];
    const float* bn2_b       = (const float*)d_in[10];
    const float* bn2_m       = (const float*)d_in[11];
    const float* bn2_v       = (const float*)d_in[12];
    const float* pr_gamma    = (const float*)d_in[13];
    const float* pr_slope    = (const float*)d_in[14];
    const float* pr_zeta     = (const float*)d_in[15];

    char* ws = (char*)d_ws;
    u64*   pw1    = (u64*)(ws);            // 256*9*4*8   = 73728 B
    u64*   pw2    = (u64*)(ws + 73728);    // 256*4*8     =  8192 B
    float* scale1 = (float*)(ws + 81920);  // 1024 B each
    float* shift1 = (float*)(ws + 82944);
    float* scale2 = (float*)(ws + 83968);
    float* shift2 = (float*)(ws + 84992);
    u64*   pack1  = (u64*)(ws + 86016);    // 32*56*56*4*8 = 3211264 B

    prep_weights<<<256, 256, 0, stream>>>(w1, w2, bn1_g, bn1_b, bn1_m, bn1_v,
                                          bn2_g, bn2_b, bn2_m, bn2_v,
                                          pw1, pw2, scale1, shift1, scale2, shift2);
    pack_input<<<BB*HH, 256, 0, stream>>>(x, rsign1_beta, pack1);
    main_fused<<<BB*HH*2, 256, 0, stream>>>(x, pack1, pw1, pw2,
                                            scale1, shift1, scale2, shift2,
                                            rsign2_beta, pr_gamma, pr_slope, pr_zeta,
                                            (float*)d_out);
}